// Round 5
// baseline (167.679 us; speedup 1.0000x reference)
//
#include <hip/hip_runtime.h>
#include <hip/hip_bf16.h>
#include <cmath>

// Problem constants
#define B_  16
#define N_  512
#define H_  8
#define F0_ 64
#define DEMB_ 64
#define FIN0_ 131   // 64 + 64 + 3
#define KP0_ 192    // padded K for layer-0 GEMM
#define O_  128
#define FIN1_ 1024  // H_*O_

typedef __attribute__((ext_vector_type(4))) float f32x4;
typedef __attribute__((ext_vector_type(8))) short bf16x8;

__device__ inline ushort f2bf(float f) {
    union { float f; unsigned u; } x; x.f = f;
    unsigned r = x.u + 0x7fff + ((x.u >> 16) & 1);   // RNE
    return (ushort)(r >> 16);
}
__device__ inline float bf2f(ushort u) {
    union { unsigned u; float f; } x; x.u = ((unsigned)u) << 16;
    return x.f;
}
__device__ inline float tanh_fast(float x) {
    x = fminf(fmaxf(x, -15.f), 15.f);
    float e = __expf(2.f * x);
    return (e - 1.f) * __frcp_rn(e + 1.f);
}

// ---------------------------------------------------------------------------
// x0p build (bf16, [8192][192], zero-padded cols 131..191 via memset)
// ---------------------------------------------------------------------------
__global__ __launch_bounds__(256) void k_copy_h(const float* __restrict__ h,
                                                ushort* __restrict__ x0) {
    int i = blockIdx.x * 256 + threadIdx.x;   // over B*N*64
    int r = i >> 6, c = i & 63;
    x0[(size_t)r * KP0_ + c] = f2bf(h[i]);
}

__global__ __launch_bounds__(256) void k_emb_norm(const int* __restrict__ verts,
                                                  const float* __restrict__ table,
                                                  const float* __restrict__ w,
                                                  const float* __restrict__ bb,
                                                  ushort* __restrict__ x0) {
    int b = blockIdx.x >> 6, c = blockIdx.x & 63;
    int t = threadIdx.x;
    float vals[2], sum = 0.f, sq = 0.f;
#pragma unroll
    for (int i = 0; i < 2; ++i) {
        int n = t + i * 256;
        int vid = verts[b * N_ + n];
        float v = table[(size_t)vid * DEMB_ + c];
        vals[i] = v; sum += v; sq += v * v;
    }
    __shared__ float s0[256], s1[256];
    s0[t] = sum; s1[t] = sq; __syncthreads();
    for (int o = 128; o > 0; o >>= 1) {
        if (t < o) { s0[t] += s0[t + o]; s1[t] += s1[t + o]; }
        __syncthreads();
    }
    float mu = s0[0] * (1.f / N_);
    float var = s1[0] * (1.f / N_) - mu * mu;
    float inv = rsqrtf(var + 1e-5f);
    float ww = w[c], bv = bb[c];
#pragma unroll
    for (int i = 0; i < 2; ++i) {
        int n = t + i * 256;
        x0[((size_t)b * N_ + n) * KP0_ + 64 + c] = f2bf((vals[i] - mu) * inv * ww + bv);
    }
}

__global__ __launch_bounds__(256) void k_ue_norm(const float* __restrict__ ue,
                                                 const float* __restrict__ w,
                                                 const float* __restrict__ bb,
                                                 ushort* __restrict__ x0) {
    int b = blockIdx.x / 3, c = blockIdx.x % 3;
    int t = threadIdx.x;
    float vals[2], sum = 0.f, sq = 0.f;
#pragma unroll
    for (int i = 0; i < 2; ++i) {
        int n = t + i * 256;
        float v = ue[((size_t)b * N_ + n) * 3 + c];
        vals[i] = v; sum += v; sq += v * v;
    }
    __shared__ float s0[256], s1[256];
    s0[t] = sum; s1[t] = sq; __syncthreads();
    for (int o = 128; o > 0; o >>= 1) {
        if (t < o) { s0[t] += s0[t + o]; s1[t] += s1[t + o]; }
        __syncthreads();
    }
    float mu = s0[0] * (1.f / N_);
    float var = s1[0] * (1.f / N_) - mu * mu;
    float inv = rsqrtf(var + 1e-5f);
    float ww = w[c], bv = bb[c];
#pragma unroll
    for (int i = 0; i < 2; ++i) {
        int n = t + i * 256;
        x0[((size_t)b * N_ + n) * KP0_ + 128 + c] = f2bf((vals[i] - mu) * inv * ww + bv);
    }
}

// ---------------------------------------------------------------------------
// Weight transpose+convert: w [H][K][128] f32 -> wt [H][128][Kp] bf16 (pad 0)
// ---------------------------------------------------------------------------
template <int K, int Kp>
__global__ __launch_bounds__(128) void k_wt(const float* __restrict__ w,
                                            ushort* __restrict__ wt) {
    int hh = blockIdx.x / (Kp / 8);
    int kc = blockIdx.x % (Kp / 8);
    int o = threadIdx.x;
    bf16x8 v;
#pragma unroll
    for (int j = 0; j < 8; ++j) {
        int k = kc * 8 + j;
        float f = (k < K) ? w[((size_t)hh * K + k) * 128 + o] : 0.f;
        v[j] = (short)f2bf(f);
    }
    *(bf16x8*)(wt + ((size_t)(hh * 128 + o)) * Kp + kc * 8) = v;
}

// ---------------------------------------------------------------------------
// adj > 0 bitmask: word (b*512+n)*8 + c holds bits for m = c*64 .. c*64+63
// ---------------------------------------------------------------------------
__global__ __launch_bounds__(256) void k_mask(const float* __restrict__ adj,
                                              unsigned long long* __restrict__ mask) {
    int gid = blockIdx.x * 256 + threadIdx.x;
    float v = adj[gid];
    unsigned long long m = __ballot(v > 0.f);
    if ((threadIdx.x & 63) == 0) mask[gid >> 6] = m;
}

// ---------------------------------------------------------------------------
// MFMA GEMM + fused s/d: hpT[bh][o][n] = sum_k A[b*512+n][k] * Wt[h][o][k]
// s[bh][n] = sum_o tanh(hp)*a_src[h][o]; d likewise (fp32 acc, pre-bf16).
// ---------------------------------------------------------------------------
template <int K>
__global__ __launch_bounds__(256) void k_gemm(const ushort* __restrict__ A,
                                              const ushort* __restrict__ Wt,
                                              const float* __restrict__ asrc,
                                              const float* __restrict__ adst,
                                              ushort* __restrict__ hpT,
                                              float* __restrict__ sout,
                                              float* __restrict__ dout) {
    __shared__ ushort As[128 * 64];
    __shared__ ushort Bs[128 * 64];
    int bid = blockIdx.x;
    int hh = bid >> 6;           // head
    int mt = bid & 63;           // 128-row tile of M=8192
    int tid = threadIdx.x;
    int wid = tid >> 6, l = tid & 63;
    int wm = wid >> 1, wn = wid & 1;

    const ushort* Ab = A + (size_t)mt * 128 * K;
    const ushort* Wb = Wt + (size_t)hh * 128 * K;

    f32x4 acc[4][4];
#pragma unroll
    for (int m = 0; m < 4; ++m)
#pragma unroll
        for (int n = 0; n < 4; ++n) acc[m][n] = (f32x4){0.f, 0.f, 0.f, 0.f};

    int srow = tid >> 3;         // 0..31
    int segp = tid & 7;          // physical 16B slot

    for (int kt = 0; kt < K / 64; ++kt) {
        int k0 = kt * 64;
#pragma unroll
        for (int it = 0; it < 4; ++it) {
            int row = it * 32 + srow;
            int segl = segp ^ (row & 7);
            __builtin_amdgcn_global_load_lds(
                (const __attribute__((address_space(1))) void*)(Ab + (size_t)row * K + k0 + segl * 8),
                (__attribute__((address_space(3))) void*)(As + (it * 32 + wid * 8) * 64),
                16, 0, 0);
            __builtin_amdgcn_global_load_lds(
                (const __attribute__((address_space(1))) void*)(Wb + (size_t)row * K + k0 + segl * 8),
                (__attribute__((address_space(3))) void*)(Bs + (it * 32 + wid * 8) * 64),
                16, 0, 0);
        }
        __syncthreads();

        int lr = l & 15;
        int kg = l >> 4;
#pragma unroll
        for (int kk = 0; kk < 2; ++kk) {
            int segl = kk * 4 + kg;
            bf16x8 a[4], b[4];
#pragma unroll
            for (int m = 0; m < 4; ++m) {
                int row = wm * 64 + m * 16 + lr;
                int sp = segl ^ (row & 7);
                a[m] = *(const bf16x8*)(As + row * 64 + sp * 8);
            }
#pragma unroll
            for (int n = 0; n < 4; ++n) {
                int row = wn * 64 + n * 16 + lr;
                int sp = segl ^ (row & 7);
                b[n] = *(const bf16x8*)(Bs + row * 64 + sp * 8);
            }
#pragma unroll
            for (int m = 0; m < 4; ++m)
#pragma unroll
                for (int n = 0; n < 4; ++n)
                    acc[m][n] = __builtin_amdgcn_mfma_f32_16x16x32_bf16(a[m], b[n], acc[m][n], 0, 0, 0);
        }
        __syncthreads();
    }

    // epilogue 1: hpT write. D col=lane&15 (o), row=(lane>>4)*4+j (n).
    int bb = mt >> 2;
    int n_in_b = (mt & 3) * 128;
    int bh = bb * H_ + hh;
    ushort* Hp = hpT + ((size_t)bh * 128) * 512;
#pragma unroll
    for (int m = 0; m < 4; ++m)
#pragma unroll
        for (int n = 0; n < 4; ++n) {
            int rr = wm * 64 + m * 16 + (l >> 4) * 4;
            int cc = wn * 64 + n * 16 + (l & 15);
            ushort4 v;
            v.x = f2bf(acc[m][n][0]);
            v.y = f2bf(acc[m][n][1]);
            v.z = f2bf(acc[m][n][2]);
            v.w = f2bf(acc[m][n][3]);
            *(ushort4*)(Hp + (size_t)cc * 512 + n_in_b + rr) = v;
        }

    // epilogue 2: fused s/d row-reduce (tanh in fp32)
    float* sP = (float*)As;          // [2][128]
    float* dP = sP + 256;            // [2][128]
    float av[4], dv[4];
#pragma unroll
    for (int n = 0; n < 4; ++n) {
        int cc = wn * 64 + n * 16 + (l & 15);
        av[n] = asrc[hh * 128 + cc];
        dv[n] = adst[hh * 128 + cc];
    }
#pragma unroll
    for (int m = 0; m < 4; ++m)
#pragma unroll
        for (int j = 0; j < 4; ++j) {
            float sv = 0.f, dvv = 0.f;
#pragma unroll
            for (int n = 0; n < 4; ++n) {
                float th = tanh_fast(acc[m][n][j]);
                sv += th * av[n];
                dvv += th * dv[n];
            }
#pragma unroll
            for (int off = 1; off < 16; off <<= 1) {
                sv += __shfl_xor(sv, off);
                dvv += __shfl_xor(dvv, off);
            }
            if ((l & 15) == 0) {
                int rr = wm * 64 + m * 16 + (l >> 4) * 4 + j;
                sP[wn * 128 + rr] = sv;
                dP[wn * 128 + rr] = dvv;
            }
        }
    __syncthreads();
    if (tid < 128) {
        sout[(size_t)bh * 512 + n_in_b + tid] = sP[tid] + sP[128 + tid];
    } else {
        int r = tid - 128;
        dout[(size_t)bh * 512 + n_in_b + r] = dP[r] + dP[128 + r];
    }
}

// ---------------------------------------------------------------------------
// Fused masked softmax + MFMA PV — 8-wave (512-thread) blocks for occupancy.
// grid 2048: b = bid&15 (XCD pin), hh = (bid>>4)&7, tile = bid>>7 (32 rows).
// Single-pass softmax (no max subtraction; |logit| <= ~55 provable bound).
// P swizzle: phys = s ^ (s>>3) ^ (row&7), s = 16B slot in row (bijective,
// same involution on write (s=c*4+j) and read (s=4*ks+lg4) sides).
// ---------------------------------------------------------------------------
union ShU {
    ushort P[32 * 512];          // 32 KB
    float  T[8][32][18];         // per-wave transpose staging (18.4 KB)
};

template <bool L0>
__global__ __launch_bounds__(512, 8) void k_attn(const ushort* __restrict__ hpT,
                                                 const float* __restrict__ sbuf,
                                                 const float* __restrict__ dbuf,
                                                 const unsigned* __restrict__ mask32,
                                                 ushort* __restrict__ out) {
    __shared__ ShU u;
    __shared__ float ds2[16 * 36];
    __shared__ float rs[32];

    int bid = blockIdx.x;
    int b = bid & 15, hh = (bid >> 4) & 7, tile = bid >> 7;
    int bh = b * 8 + hh;
    int n0 = tile * 32;
    int t = threadIdx.x;

    int row = t >> 4, c = t & 15;
    // hoisted independent global loads
    unsigned mw = mask32[((size_t)(b * 512 + n0 + row) << 4) + c];
    float sv = sbuf[(size_t)bh * 512 + n0 + row];

    // stage d: chunk-padded layout, index (m>>5)*36 + (m&31)
    ds2[(t >> 5) * 36 + (t & 31)] = dbuf[(size_t)bh * 512 + t];
    __syncthreads();

    // ---- single-pass softmax: unnormalized e -> P, rowsum -> rs ----
    const float* dsc = ds2 + c * 36;
    float sum = 0.f;
#pragma unroll
    for (int j = 0; j < 4; ++j) {
        f32x4 da = *(const f32x4*)(dsc + j * 8);
        f32x4 db2 = *(const f32x4*)(dsc + j * 8 + 4);
        float ev[8];
#pragma unroll
        for (int q = 0; q < 8; ++q) {
            float dm = (q < 4) ? da[q] : db2[q - 4];
            float lg = sv + dm;
            lg = fmaxf(lg, 0.2f * lg);               // leaky_relu(0.2)
            float e = ((mw >> (j * 8 + q)) & 1) ? __expf(lg) : 0.f;
            sum += e;
            ev[q] = e;
        }
        unsigned p01, p23, p45, p67;
        asm("v_cvt_pk_bf16_f32 %0, %1, %2" : "=v"(p01) : "v"(ev[0]), "v"(ev[1]));
        asm("v_cvt_pk_bf16_f32 %0, %1, %2" : "=v"(p23) : "v"(ev[2]), "v"(ev[3]));
        asm("v_cvt_pk_bf16_f32 %0, %1, %2" : "=v"(p45) : "v"(ev[4]), "v"(ev[5]));
        asm("v_cvt_pk_bf16_f32 %0, %1, %2" : "=v"(p67) : "v"(ev[6]), "v"(ev[7]));
        int s = c * 4 + j;
        int phys = s ^ (c >> 1) ^ (row & 7);
        uint4 pk4 = {p01, p23, p45, p67};
        *(uint4*)((char*)u.P + row * 1024 + phys * 16) = pk4;
    }
    sum += __shfl_xor(sum, 1);
    sum += __shfl_xor(sum, 2);
    sum += __shfl_xor(sum, 4);
    sum += __shfl_xor(sum, 8);
    if (c == 0) rs[row] = sum;
    __syncthreads();

    // ---- PV: each wave o-16 x n-32, O^T = V^T x P^T via MFMA ----
    int wid = t >> 6, l = t & 63;
    int lr = l & 15, lg4 = l >> 4;
    int ob = wid * 16;
    const ushort* Ab = hpT + ((size_t)(bh * 128 + ob + lr)) * 512 + lg4 * 8;

    f32x4 acc[2];
    acc[0] = (f32x4){0.f, 0.f, 0.f, 0.f};
    acc[1] = (f32x4){0.f, 0.f, 0.f, 0.f};

#pragma unroll
    for (int ks = 0; ks < 16; ++ks) {
        int phys = (4 * ks + lg4) ^ (ks >> 1) ^ (lr & 7);
        bf16x8 a = *(const bf16x8*)(Ab + ks * 32);
        bf16x8 b0 = *(const bf16x8*)((const char*)u.P + lr * 1024 + phys * 16);
        bf16x8 b1 = *(const bf16x8*)((const char*)u.P + (lr + 16) * 1024 + phys * 16);
        acc[0] = __builtin_amdgcn_mfma_f32_16x16x32_bf16(a, b0, acc[0], 0, 0, 0);
        acc[1] = __builtin_amdgcn_mfma_f32_16x16x32_bf16(a, b1, acc[1], 0, 0, 0);
    }
    __syncthreads();   // all waves done reading P before T overwrites it

    // normalize + per-wave transpose through LDS
    float rinv0 = __frcp_rn(rs[lr]);
    float rinv1 = __frcp_rn(rs[16 + lr]);
#pragma unroll
    for (int nf = 0; nf < 2; ++nf) {
        float ri = nf ? rinv1 : rinv0;
#pragma unroll
        for (int j = 0; j < 4; ++j)
            u.T[wid][nf * 16 + lr][lg4 * 4 + j] = acc[nf][j] * ri;
    }
    __syncthreads();

    int nr = l >> 1, oh = l & 1;
    ushort* op;
    if (L0)
        op = out + ((size_t)(b * 512 + n0 + nr)) * FIN1_ + hh * 128 + ob + oh * 8;
    else
        op = out + ((size_t)bh * 512 + n0 + nr) * 128 + ob + oh * 8;

    bf16x8 wv;
#pragma unroll
    for (int j = 0; j < 2; ++j) {
        f32x4 v = *(const f32x4*)&u.T[wid][nr][oh * 8 + j * 4];
#pragma unroll
        for (int q = 0; q < 4; ++q) {
            float f = v[q];
            if (L0) f = (f > 0.f) ? f : expm1f(f);
            wv[j * 4 + q] = (short)f2bf(f);
        }
    }
    *(bf16x8*)op = wv;
}

// ---------------------------------------------------------------------------
// mean over heads (bf16 in) + log_softmax over channels(128)
// ---------------------------------------------------------------------------
__global__ __launch_bounds__(128) void k_out(const ushort* __restrict__ o1,
                                             float* __restrict__ out) {
    int row = blockIdx.x;       // b*512+n
    int b = row >> 9, n = row & 511;
    int t = threadIdx.x;
    float v = 0.f;
#pragma unroll
    for (int hh = 0; hh < H_; ++hh)
        v += bf2f(o1[((size_t)(b * H_ + hh) * N_ + n) * O_ + t]);
    v *= 0.125f;
    float m = v;
#pragma unroll
    for (int off = 32; off > 0; off >>= 1) m = fmaxf(m, __shfl_down(m, off));
    __shared__ float red[4];
    if ((t & 63) == 0) red[t >> 6] = m;
    __syncthreads();
    float rm = fmaxf(red[0], red[1]);
    float e = __expf(v - rm);
    float ss = e;
#pragma unroll
    for (int off = 32; off > 0; off >>= 1) ss += __shfl_down(ss, off);
    if ((t & 63) == 0) red[2 + (t >> 6)] = ss;
    __syncthreads();
    float rs2 = red[2] + red[3];
    out[(size_t)row * O_ + t] = v - rm - logf(rs2);
}

// ---------------------------------------------------------------------------
extern "C" void kernel_launch(void* const* d_in, const int* in_sizes, int n_in,
                              void* d_out, int out_size, void* d_ws, size_t ws_size,
                              hipStream_t stream) {
    const int*   verts = (const int*)d_in[0];
    const float* adj   = (const float*)d_in[1];
    const float* h     = (const float*)d_in[2];
    const float* ue    = (const float*)d_in[3];
    const float* table = (const float*)d_in[4];
    const float* n1w   = (const float*)d_in[5];
    const float* n1b   = (const float*)d_in[6];
    const float* n2w   = (const float*)d_in[7];
    const float* n2b   = (const float*)d_in[8];
    const float* w0    = (const float*)d_in[9];
    const float* as0   = (const float*)d_in[10];
    const float* ad0   = (const float*)d_in[11];
    const float* w1    = (const float*)d_in[12];
    const float* as1   = (const float*)d_in[13];
    const float* ad1   = (const float*)d_in[14];
    float* out = (float*)d_out;

    // workspace layout (ushort units)
    ushort* x0p  = (ushort*)d_ws;                 // 1,572,864
    ushort* wt0  = x0p + 1572864;                 // 196,608
    ushort* wt1  = wt0 + 196608;                  // 1,048,576
    ushort* hpT  = wt1 + 1048576;                 // 8,388,608
    ushort* x1bf = hpT + 8388608;                 // 8,388,608
    ushort* o1   = x1bf + 8388608;                // 8,388,608
    unsigned long long* mask = (unsigned long long*)(o1 + 8388608);  // 65,536 words
    float* sb = (float*)(mask + 65536);           // 65,536 f
    float* db = sb + 65536;                       // 65,536 f

    hipMemsetAsync(x0p, 0, (size_t)8192 * KP0_ * sizeof(ushort), stream);
    hipLaunchKernelGGL(k_copy_h,   dim3(2048), dim3(256), 0, stream, h, x0p);
    hipLaunchKernelGGL(k_emb_norm, dim3(1024), dim3(256), 0, stream, verts, table, n1w, n1b, x0p);
    hipLaunchKernelGGL(k_ue_norm,  dim3(48),   dim3(256), 0, stream, ue, n2w, n2b, x0p);
    hipLaunchKernelGGL((k_wt<FIN0_, KP0_>), dim3(8 * (KP0_ / 8)), dim3(128), 0, stream, w0, wt0);
    hipLaunchKernelGGL((k_wt<FIN1_, FIN1_>), dim3(8 * (FIN1_ / 8)), dim3(128), 0, stream, w1, wt1);
    hipLaunchKernelGGL(k_mask, dim3(16384), dim3(256), 0, stream, adj, mask);

    // layer 0 (s/d fused into GEMM epilogue)
    hipLaunchKernelGGL((k_gemm<KP0_>), dim3(512), dim3(256), 0, stream,
                       x0p, wt0, as0, ad0, hpT, sb, db);
    hipLaunchKernelGGL((k_attn<true>), dim3(2048), dim3(512), 0, stream,
                       hpT, sb, db, (const unsigned*)mask, x1bf);

    // layer 1
    hipLaunchKernelGGL((k_gemm<FIN1_>), dim3(512), dim3(256), 0, stream,
                       x1bf, wt1, as1, ad1, hpT, sb, db);
    hipLaunchKernelGGL((k_attn<false>), dim3(2048), dim3(512), 0, stream,
                       hpT, sb, db, (const unsigned*)mask, o1);

    // mean over heads + log_softmax
    hipLaunchKernelGGL(k_out, dim3(8192), dim3(128), 0, stream, o1, out);
}

// Round 6
// 143.065 us; speedup vs baseline: 1.1721x; 1.1721x over previous
//
#include <hip/hip_runtime.h>
#include <hip/hip_bf16.h>
#include <cmath>

// Problem constants
#define B_  16
#define N_  512
#define H_  8
#define F0_ 64
#define DEMB_ 64
#define FIN0_ 131   // 64 + 64 + 3
#define KP0_ 192    // padded K for layer-0 GEMM
#define O_  128
#define FIN1_ 1024  // H_*O_

typedef __attribute__((ext_vector_type(4))) float f32x4;
typedef __attribute__((ext_vector_type(8))) short bf16x8;

__device__ inline ushort f2bf(float f) {
    union { float f; unsigned u; } x; x.f = f;
    unsigned r = x.u + 0x7fff + ((x.u >> 16) & 1);   // RNE
    return (ushort)(r >> 16);
}
__device__ inline float bf2f(ushort u) {
    union { unsigned u; float f; } x; x.u = ((unsigned)u) << 16;
    return x.f;
}
__device__ inline float tanh_fast(float x) {
    x = fminf(fmaxf(x, -15.f), 15.f);
    float e = __expf(2.f * x);
    return (e - 1.f) * __frcp_rn(e + 1.f);
}

// ---------------------------------------------------------------------------
// x0p build (bf16, [8192][192], zero-padded cols 131..191 via memset)
// ---------------------------------------------------------------------------
__global__ __launch_bounds__(256) void k_copy_h(const float* __restrict__ h,
                                                ushort* __restrict__ x0) {
    int i = blockIdx.x * 256 + threadIdx.x;   // over B*N*64
    int r = i >> 6, c = i & 63;
    x0[(size_t)r * KP0_ + c] = f2bf(h[i]);
}

__global__ __launch_bounds__(256) void k_emb_norm(const int* __restrict__ verts,
                                                  const float* __restrict__ table,
                                                  const float* __restrict__ w,
                                                  const float* __restrict__ bb,
                                                  ushort* __restrict__ x0) {
    int b = blockIdx.x >> 6, c = blockIdx.x & 63;
    int t = threadIdx.x;
    float vals[2], sum = 0.f, sq = 0.f;
#pragma unroll
    for (int i = 0; i < 2; ++i) {
        int n = t + i * 256;
        int vid = verts[b * N_ + n];
        float v = table[(size_t)vid * DEMB_ + c];
        vals[i] = v; sum += v; sq += v * v;
    }
    __shared__ float s0[256], s1[256];
    s0[t] = sum; s1[t] = sq; __syncthreads();
    for (int o = 128; o > 0; o >>= 1) {
        if (t < o) { s0[t] += s0[t + o]; s1[t] += s1[t + o]; }
        __syncthreads();
    }
    float mu = s0[0] * (1.f / N_);
    float var = s1[0] * (1.f / N_) - mu * mu;
    float inv = rsqrtf(var + 1e-5f);
    float ww = w[c], bv = bb[c];
#pragma unroll
    for (int i = 0; i < 2; ++i) {
        int n = t + i * 256;
        x0[((size_t)b * N_ + n) * KP0_ + 64 + c] = f2bf((vals[i] - mu) * inv * ww + bv);
    }
}

__global__ __launch_bounds__(256) void k_ue_norm(const float* __restrict__ ue,
                                                 const float* __restrict__ w,
                                                 const float* __restrict__ bb,
                                                 ushort* __restrict__ x0) {
    int b = blockIdx.x / 3, c = blockIdx.x % 3;
    int t = threadIdx.x;
    float vals[2], sum = 0.f, sq = 0.f;
#pragma unroll
    for (int i = 0; i < 2; ++i) {
        int n = t + i * 256;
        float v = ue[((size_t)b * N_ + n) * 3 + c];
        vals[i] = v; sum += v; sq += v * v;
    }
    __shared__ float s0[256], s1[256];
    s0[t] = sum; s1[t] = sq; __syncthreads();
    for (int o = 128; o > 0; o >>= 1) {
        if (t < o) { s0[t] += s0[t + o]; s1[t] += s1[t + o]; }
        __syncthreads();
    }
    float mu = s0[0] * (1.f / N_);
    float var = s1[0] * (1.f / N_) - mu * mu;
    float inv = rsqrtf(var + 1e-5f);
    float ww = w[c], bv = bb[c];
#pragma unroll
    for (int i = 0; i < 2; ++i) {
        int n = t + i * 256;
        x0[((size_t)b * N_ + n) * KP0_ + 128 + c] = f2bf((vals[i] - mu) * inv * ww + bv);
    }
}

// ---------------------------------------------------------------------------
// Weight transpose+convert: w [H][K][128] f32 -> wt [H][128][Kp] bf16 (pad 0)
// ---------------------------------------------------------------------------
template <int K, int Kp>
__global__ __launch_bounds__(128) void k_wt(const float* __restrict__ w,
                                            ushort* __restrict__ wt) {
    int hh = blockIdx.x / (Kp / 8);
    int kc = blockIdx.x % (Kp / 8);
    int o = threadIdx.x;
    bf16x8 v;
#pragma unroll
    for (int j = 0; j < 8; ++j) {
        int k = kc * 8 + j;
        float f = (k < K) ? w[((size_t)hh * K + k) * 128 + o] : 0.f;
        v[j] = (short)f2bf(f);
    }
    *(bf16x8*)(wt + ((size_t)(hh * 128 + o)) * Kp + kc * 8) = v;
}

// ---------------------------------------------------------------------------
// adj > 0 bitmask: word (b*512+n)*8 + c holds bits for m = c*64 .. c*64+63
// ---------------------------------------------------------------------------
__global__ __launch_bounds__(256) void k_mask(const float* __restrict__ adj,
                                              unsigned long long* __restrict__ mask) {
    int gid = blockIdx.x * 256 + threadIdx.x;
    float v = adj[gid];
    unsigned long long m = __ballot(v > 0.f);
    if ((threadIdx.x & 63) == 0) mask[gid >> 6] = m;
}

// ---------------------------------------------------------------------------
// MFMA GEMM + fused s/d: hpT[bh][o][n] = sum_k A[b*512+n][k] * Wt[h][o][k]
// s[bh][n] = sum_o tanh(hp)*a_src[h][o]; d likewise (fp32 acc, pre-bf16).
// bid: hh = bid&7 (head pinned to XCD), mt = bid>>3.
// ---------------------------------------------------------------------------
template <int K>
__global__ __launch_bounds__(256) void k_gemm(const ushort* __restrict__ A,
                                              const ushort* __restrict__ Wt,
                                              const float* __restrict__ asrc,
                                              const float* __restrict__ adst,
                                              ushort* __restrict__ hpT,
                                              float* __restrict__ sout,
                                              float* __restrict__ dout) {
    __shared__ ushort As[128 * 64];
    __shared__ ushort Bs[128 * 64];
    int bid = blockIdx.x;
    int hh = bid & 7;            // head (XCD-pinned)
    int mt = bid >> 3;           // 128-row tile of M=8192
    int tid = threadIdx.x;
    int wid = tid >> 6, l = tid & 63;
    int wm = wid >> 1, wn = wid & 1;

    const ushort* Ab = A + (size_t)mt * 128 * K;
    const ushort* Wb = Wt + (size_t)hh * 128 * K;

    f32x4 acc[4][4];
#pragma unroll
    for (int m = 0; m < 4; ++m)
#pragma unroll
        for (int n = 0; n < 4; ++n) acc[m][n] = (f32x4){0.f, 0.f, 0.f, 0.f};

    int srow = tid >> 3;         // 0..31
    int segp = tid & 7;          // physical 16B slot

    for (int kt = 0; kt < K / 64; ++kt) {
        int k0 = kt * 64;
#pragma unroll
        for (int it = 0; it < 4; ++it) {
            int row = it * 32 + srow;
            int segl = segp ^ (row & 7);
            __builtin_amdgcn_global_load_lds(
                (const __attribute__((address_space(1))) void*)(Ab + (size_t)row * K + k0 + segl * 8),
                (__attribute__((address_space(3))) void*)(As + (it * 32 + wid * 8) * 64),
                16, 0, 0);
            __builtin_amdgcn_global_load_lds(
                (const __attribute__((address_space(1))) void*)(Wb + (size_t)row * K + k0 + segl * 8),
                (__attribute__((address_space(3))) void*)(Bs + (it * 32 + wid * 8) * 64),
                16, 0, 0);
        }
        __syncthreads();

        int lr = l & 15;
        int kg = l >> 4;
#pragma unroll
        for (int kk = 0; kk < 2; ++kk) {
            int segl = kk * 4 + kg;
            bf16x8 a[4], b[4];
#pragma unroll
            for (int m = 0; m < 4; ++m) {
                int row = wm * 64 + m * 16 + lr;
                int sp = segl ^ (row & 7);
                a[m] = *(const bf16x8*)(As + row * 64 + sp * 8);
            }
#pragma unroll
            for (int n = 0; n < 4; ++n) {
                int row = wn * 64 + n * 16 + lr;
                int sp = segl ^ (row & 7);
                b[n] = *(const bf16x8*)(Bs + row * 64 + sp * 8);
            }
#pragma unroll
            for (int m = 0; m < 4; ++m)
#pragma unroll
                for (int n = 0; n < 4; ++n)
                    acc[m][n] = __builtin_amdgcn_mfma_f32_16x16x32_bf16(a[m], b[n], acc[m][n], 0, 0, 0);
        }
        __syncthreads();
    }

    // epilogue 1: hpT write. D col=lane&15 (o), row=(lane>>4)*4+j (n).
    int bb = mt >> 2;
    int n_in_b = (mt & 3) * 128;
    int bh = bb * H_ + hh;
    ushort* Hp = hpT + ((size_t)bh * 128) * 512;
#pragma unroll
    for (int m = 0; m < 4; ++m)
#pragma unroll
        for (int n = 0; n < 4; ++n) {
            int rr = wm * 64 + m * 16 + (l >> 4) * 4;
            int cc = wn * 64 + n * 16 + (l & 15);
            ushort4 v;
            v.x = f2bf(acc[m][n][0]);
            v.y = f2bf(acc[m][n][1]);
            v.z = f2bf(acc[m][n][2]);
            v.w = f2bf(acc[m][n][3]);
            *(ushort4*)(Hp + (size_t)cc * 512 + n_in_b + rr) = v;
        }

    // epilogue 2: fused s/d row-reduce (tanh in fp32)
    float* sP = (float*)As;          // [2][128]
    float* dP = sP + 256;            // [2][128]
    float av[4], dv[4];
#pragma unroll
    for (int n = 0; n < 4; ++n) {
        int cc = wn * 64 + n * 16 + (l & 15);
        av[n] = asrc[hh * 128 + cc];
        dv[n] = adst[hh * 128 + cc];
    }
#pragma unroll
    for (int m = 0; m < 4; ++m)
#pragma unroll
        for (int j = 0; j < 4; ++j) {
            float sv = 0.f, dvv = 0.f;
#pragma unroll
            for (int n = 0; n < 4; ++n) {
                float th = tanh_fast(acc[m][n][j]);
                sv += th * av[n];
                dvv += th * dv[n];
            }
#pragma unroll
            for (int off = 1; off < 16; off <<= 1) {
                sv += __shfl_xor(sv, off);
                dvv += __shfl_xor(dvv, off);
            }
            if ((l & 15) == 0) {
                int rr = wm * 64 + m * 16 + (l >> 4) * 4 + j;
                sP[wn * 128 + rr] = sv;
                dP[wn * 128 + rr] = dvv;
            }
        }
    __syncthreads();
    if (tid < 128) {
        sout[(size_t)bh * 512 + n_in_b + tid] = sP[tid] + sP[128 + tid];
    } else {
        int r = tid - 128;
        dout[(size_t)bh * 512 + n_in_b + r] = dP[r] + dP[128 + r];
    }
}

// ---------------------------------------------------------------------------
// Fused masked softmax + PV as a tiled GEMM with generated-A.
// grid 512: xcd=bid&7, idx=bid>>3, bh = xcd + 8*(idx&15), tile = idx>>4.
// Block: 256 threads (2x2 waves of 64x64), output tile n-128 x o-128.
// K = m = 512 in 8 chunks of 64:
//   stage V-chunk [128 o][64 m] from hpT via global_load_lds (XOR swizzle)
//   softmax: each thread (row=t>>1, mh=t&1) computes 32 unnormalized e's ->
//            P-chunk [128 n][64 m] in LDS (same XOR swizzle)
//   barrier; 32 MFMA/wave (A=V [o][m], B=P [n][m], D[o][n]); barrier.
// Epilogue: rowsum reduce -> normalize + (ELU) in-register -> ushort4 stores.
// ---------------------------------------------------------------------------
template <bool L0>
__global__ __launch_bounds__(256, 2) void k_attn(const ushort* __restrict__ hpT,
                                                 const float* __restrict__ sbuf,
                                                 const float* __restrict__ dbuf,
                                                 const unsigned* __restrict__ mask32,
                                                 ushort* __restrict__ out) {
    __shared__ ushort Vbuf[128 * 64];
    __shared__ ushort Abuf[128 * 64];
    __shared__ float dsh[512];
    __shared__ float rsh[128];

    int bid = blockIdx.x;
    int xcd = bid & 7, idx = bid >> 3;
    int bh = xcd + 8 * (idx & 15);
    int tile = idx >> 4;             // 0..3
    int b = bh >> 3, hh = bh & 7;
    int n0 = tile * 128;
    int t = threadIdx.x;
    int wid = t >> 6, l = t & 63;
    int wm = wid >> 1, wn = wid & 1;
    int lr = l & 15, kg = l >> 4;

    const ushort* Vb = hpT + (size_t)bh * 128 * 512;   // [o][node]

    // per-thread softmax assignment: row 0..127, m-half 0..1
    int row = t >> 1, mh = t & 1;
    float sv = sbuf[(size_t)bh * 512 + n0 + row];
    unsigned mw[8];
#pragma unroll
    for (int c = 0; c < 8; ++c)
        mw[c] = mask32[((size_t)(b * 512 + n0 + row) << 4) + c * 2 + mh];

    // stage d
    dsh[t] = dbuf[(size_t)bh * 512 + t];
    dsh[256 + t] = dbuf[(size_t)bh * 512 + 256 + t];
    __syncthreads();

    f32x4 acc[4][4];
#pragma unroll
    for (int m = 0; m < 4; ++m)
#pragma unroll
        for (int n = 0; n < 4; ++n) acc[m][n] = (f32x4){0.f, 0.f, 0.f, 0.f};

    float rsum = 0.f;
    int srow = t >> 3, segp = t & 7;

    for (int c = 0; c < 8; ++c) {
        int m0 = c * 64;
        // stage V chunk (overlaps with softmax below; barrier drains both)
#pragma unroll
        for (int it = 0; it < 4; ++it) {
            int rrow = it * 32 + srow;
            int segl = segp ^ (rrow & 7);
            __builtin_amdgcn_global_load_lds(
                (const __attribute__((address_space(1))) void*)(Vb + (size_t)rrow * 512 + m0 + segl * 8),
                (__attribute__((address_space(3))) void*)(Vbuf + (it * 32 + wid * 8) * 64),
                16, 0, 0);
        }

        // softmax: 32 logits -> unnormalized e -> P chunk
        const float* dp = dsh + m0 + mh * 32;
        unsigned mwc = mw[c];
#pragma unroll
        for (int j = 0; j < 4; ++j) {
            f32x4 da = *(const f32x4*)(dp + j * 8);
            f32x4 db2 = *(const f32x4*)(dp + j * 8 + 4);
            float ev[8];
#pragma unroll
            for (int q = 0; q < 8; ++q) {
                float dm = (q < 4) ? da[q] : db2[q - 4];
                float lg = sv + dm;
                lg = fmaxf(lg, 0.2f * lg);           // leaky_relu(0.2)
                float e = ((mwc >> (j * 8 + q)) & 1) ? __expf(lg) : 0.f;
                rsum += e;
                ev[q] = e;
            }
            unsigned p01, p23, p45, p67;
            asm("v_cvt_pk_bf16_f32 %0, %1, %2" : "=v"(p01) : "v"(ev[0]), "v"(ev[1]));
            asm("v_cvt_pk_bf16_f32 %0, %1, %2" : "=v"(p23) : "v"(ev[2]), "v"(ev[3]));
            asm("v_cvt_pk_bf16_f32 %0, %1, %2" : "=v"(p45) : "v"(ev[4]), "v"(ev[5]));
            asm("v_cvt_pk_bf16_f32 %0, %1, %2" : "=v"(p67) : "v"(ev[6]), "v"(ev[7]));
            int s = mh * 4 + j;
            int phys = s ^ (row & 7);
            uint4 pk4 = {p01, p23, p45, p67};
            *(uint4*)((char*)Abuf + row * 128 + phys * 16) = pk4;
        }
        __syncthreads();

        // MFMA: D[o][n] += V[o][m-chunk] . P[n][m-chunk]
#pragma unroll
        for (int kk = 0; kk < 2; ++kk) {
            int s = kk * 4 + kg;
            bf16x8 a[4], bfr[4];
#pragma unroll
            for (int m = 0; m < 4; ++m) {
                int rw = wm * 64 + m * 16 + lr;
                int sp = s ^ (rw & 7);
                a[m] = *(const bf16x8*)(Vbuf + rw * 64 + sp * 8);
            }
#pragma unroll
            for (int n = 0; n < 4; ++n) {
                int rw = wn * 64 + n * 16 + lr;
                int sp = s ^ (rw & 7);
                bfr[n] = *(const bf16x8*)(Abuf + rw * 64 + sp * 8);
            }
#pragma unroll
            for (int m = 0; m < 4; ++m)
#pragma unroll
                for (int n = 0; n < 4; ++n)
                    acc[m][n] = __builtin_amdgcn_mfma_f32_16x16x32_bf16(a[m], bfr[n], acc[m][n], 0, 0, 0);
        }
        __syncthreads();
    }

    // rowsum: threads t, t^1 cover the two m-halves of row t>>1
    rsum += __shfl_xor(rsum, 1);
    if ((t & 1) == 0) rsh[row] = rsum;
    __syncthreads();

    // epilogue: normalize + (ELU) + direct ushort4 stores (D rows=o, cols=n)
#pragma unroll
    for (int n = 0; n < 4; ++n) {
        int nn = wn * 64 + n * 16 + lr;
        float ri = __frcp_rn(rsh[nn]);
        size_t orow;
        if (L0)
            orow = ((size_t)(b * 512 + n0 + nn)) * FIN1_ + hh * 128;
        else
            orow = ((size_t)bh * 512 + n0 + nn) * 128;
#pragma unroll
        for (int m = 0; m < 4; ++m) {
            int o0 = wm * 64 + m * 16 + kg * 4;
            f32x4 v = acc[m][n];
            ushort4 w;
            float f0 = v[0] * ri, f1 = v[1] * ri, f2 = v[2] * ri, f3 = v[3] * ri;
            if (L0) {
                f0 = (f0 > 0.f) ? f0 : expm1f(f0);
                f1 = (f1 > 0.f) ? f1 : expm1f(f1);
                f2 = (f2 > 0.f) ? f2 : expm1f(f2);
                f3 = (f3 > 0.f) ? f3 : expm1f(f3);
            }
            w.x = f2bf(f0); w.y = f2bf(f1); w.z = f2bf(f2); w.w = f2bf(f3);
            *(ushort4*)(out + orow + o0) = w;
        }
    }
}

// ---------------------------------------------------------------------------
// mean over heads (bf16 in) + log_softmax over channels(128)
// ---------------------------------------------------------------------------
__global__ __launch_bounds__(128) void k_out(const ushort* __restrict__ o1,
                                             float* __restrict__ out) {
    int row = blockIdx.x;       // b*512+n
    int b = row >> 9, n = row & 511;
    int t = threadIdx.x;
    float v = 0.f;
#pragma unroll
    for (int hh = 0; hh < H_; ++hh)
        v += bf2f(o1[((size_t)(b * H_ + hh) * N_ + n) * O_ + t]);
    v *= 0.125f;
    float m = v;
#pragma unroll
    for (int off = 32; off > 0; off >>= 1) m = fmaxf(m, __shfl_down(m, off));
    __shared__ float red[4];
    if ((t & 63) == 0) red[t >> 6] = m;
    __syncthreads();
    float rm = fmaxf(red[0], red[1]);
    float e = __expf(v - rm);
    float ss = e;
#pragma unroll
    for (int off = 32; off > 0; off >>= 1) ss += __shfl_down(ss, off);
    if ((t & 63) == 0) red[2 + (t >> 6)] = ss;
    __syncthreads();
    float rs2 = red[2] + red[3];
    out[(size_t)row * O_ + t] = v - rm - logf(rs2);
}

// ---------------------------------------------------------------------------
extern "C" void kernel_launch(void* const* d_in, const int* in_sizes, int n_in,
                              void* d_out, int out_size, void* d_ws, size_t ws_size,
                              hipStream_t stream) {
    const int*   verts = (const int*)d_in[0];
    const float* adj   = (const float*)d_in[1];
    const float* h     = (const float*)d_in[2];
    const float* ue    = (const float*)d_in[3];
    const float* table = (const float*)d_in[4];
    const float* n1w   = (const float*)d_in[5];
    const float* n1b   = (const float*)d_in[6];
    const float* n2w   = (const float*)d_in[7];
    const float* n2b   = (const float*)d_in[8];
    const float* w0    = (const float*)d_in[9];
    const float* as0   = (const float*)d_in[10];
    const float* ad0   = (const float*)d_in[11];
    const float* w1    = (const float*)d_in[12];
    const float* as1   = (const float*)d_in[13];
    const float* ad1   = (const float*)d_in[14];
    float* out = (float*)d_out;

    // workspace layout (ushort units)
    ushort* x0p  = (ushort*)d_ws;                 // 1,572,864
    ushort* wt0  = x0p + 1572864;                 // 196,608
    ushort* wt1  = wt0 + 196608;                  // 1,048,576
    ushort* hpT  = wt1 + 1048576;                 // 8,388,608
    ushort* x1bf = hpT + 8388608;                 // 8,388,608
    ushort* o1   = x1bf + 8388608;                // 8,388,608
    unsigned long long* mask = (unsigned long long*)(o1 + 8388608);  // 65,536 words
    float* sb = (float*)(mask + 65536);           // 65,536 f
    float* db = sb + 65536;                       // 65,536 f

    hipMemsetAsync(x0p, 0, (size_t)8192 * KP0_ * sizeof(ushort), stream);
    hipLaunchKernelGGL(k_copy_h,   dim3(2048), dim3(256), 0, stream, h, x0p);
    hipLaunchKernelGGL(k_emb_norm, dim3(1024), dim3(256), 0, stream, verts, table, n1w, n1b, x0p);
    hipLaunchKernelGGL(k_ue_norm,  dim3(48),   dim3(256), 0, stream, ue, n2w, n2b, x0p);
    hipLaunchKernelGGL((k_wt<FIN0_, KP0_>), dim3(8 * (KP0_ / 8)), dim3(128), 0, stream, w0, wt0);
    hipLaunchKernelGGL((k_wt<FIN1_, FIN1_>), dim3(8 * (FIN1_ / 8)), dim3(128), 0, stream, w1, wt1);
    hipLaunchKernelGGL(k_mask, dim3(16384), dim3(256), 0, stream, adj, mask);

    // layer 0 (s/d fused into GEMM epilogue)
    hipLaunchKernelGGL((k_gemm<KP0_>), dim3(512), dim3(256), 0, stream,
                       x0p, wt0, as0, ad0, hpT, sb, db);
    hipLaunchKernelGGL((k_attn<true>), dim3(512), dim3(256), 0, stream,
                       hpT, sb, db, (const unsigned*)mask, x1bf);

    // layer 1
    hipLaunchKernelGGL((k_gemm<FIN1_>), dim3(512), dim3(256), 0, stream,
                       x1bf, wt1, as1, ad1, hpT, sb, db);
    hipLaunchKernelGGL((k_attn<false>), dim3(512), dim3(256), 0, stream,
                       hpT, sb, db, (const unsigned*)mask, o1);

    // mean over heads + log_softmax
    hipLaunchKernelGGL(k_out, dim3(8192), dim3(128), 0, stream, o1, out);
}

// Round 7
// 140.240 us; speedup vs baseline: 1.1957x; 1.0201x over previous
//
#include <hip/hip_runtime.h>
#include <hip/hip_bf16.h>
#include <cmath>

// Problem constants
#define B_  16
#define N_  512
#define H_  8
#define F0_ 64
#define DEMB_ 64
#define FIN0_ 131   // 64 + 64 + 3
#define KP0_ 192    // padded K for layer-0 GEMM
#define O_  128
#define FIN1_ 1024  // H_*O_

typedef __attribute__((ext_vector_type(4))) float f32x4;
typedef __attribute__((ext_vector_type(8))) short bf16x8;

__device__ inline ushort f2bf(float f) {
    union { float f; unsigned u; } x; x.f = f;
    unsigned r = x.u + 0x7fff + ((x.u >> 16) & 1);   // RNE
    return (ushort)(r >> 16);
}
__device__ inline float bf2f(ushort u) {
    union { unsigned u; float f; } x; x.u = ((unsigned)u) << 16;
    return x.f;
}
__device__ inline float tanh_fast(float x) {
    x = fminf(fmaxf(x, -15.f), 15.f);
    float e = __expf(2.f * x);
    return (e - 1.f) * __frcp_rn(e + 1.f);
}

// ---------------------------------------------------------------------------
// x0p build (bf16, [8192][192]).  k_copy_h writes h (cols 0..63) AND zeros
// cols 128..191 (k_ue_norm later overwrites 128..130 — stream order).
// ---------------------------------------------------------------------------
__global__ __launch_bounds__(256) void k_copy_h(const float* __restrict__ h,
                                                ushort* __restrict__ x0) {
    int i = blockIdx.x * 256 + threadIdx.x;   // over B*N*64
    int r = i >> 6, c = i & 63;
    x0[(size_t)r * KP0_ + c] = f2bf(h[i]);
    x0[(size_t)r * KP0_ + 128 + c] = 0;
}

__global__ __launch_bounds__(256) void k_emb_norm(const int* __restrict__ verts,
                                                  const float* __restrict__ table,
                                                  const float* __restrict__ w,
                                                  const float* __restrict__ bb,
                                                  ushort* __restrict__ x0) {
    int b = blockIdx.x >> 6, c = blockIdx.x & 63;
    int t = threadIdx.x;
    float vals[2], sum = 0.f, sq = 0.f;
#pragma unroll
    for (int i = 0; i < 2; ++i) {
        int n = t + i * 256;
        int vid = verts[b * N_ + n];
        float v = table[(size_t)vid * DEMB_ + c];
        vals[i] = v; sum += v; sq += v * v;
    }
    __shared__ float s0[256], s1[256];
    s0[t] = sum; s1[t] = sq; __syncthreads();
    for (int o = 128; o > 0; o >>= 1) {
        if (t < o) { s0[t] += s0[t + o]; s1[t] += s1[t + o]; }
        __syncthreads();
    }
    float mu = s0[0] * (1.f / N_);
    float var = s1[0] * (1.f / N_) - mu * mu;
    float inv = rsqrtf(var + 1e-5f);
    float ww = w[c], bv = bb[c];
#pragma unroll
    for (int i = 0; i < 2; ++i) {
        int n = t + i * 256;
        x0[((size_t)b * N_ + n) * KP0_ + 64 + c] = f2bf((vals[i] - mu) * inv * ww + bv);
    }
}

__global__ __launch_bounds__(256) void k_ue_norm(const float* __restrict__ ue,
                                                 const float* __restrict__ w,
                                                 const float* __restrict__ bb,
                                                 ushort* __restrict__ x0) {
    int b = blockIdx.x / 3, c = blockIdx.x % 3;
    int t = threadIdx.x;
    float vals[2], sum = 0.f, sq = 0.f;
#pragma unroll
    for (int i = 0; i < 2; ++i) {
        int n = t + i * 256;
        float v = ue[((size_t)b * N_ + n) * 3 + c];
        vals[i] = v; sum += v; sq += v * v;
    }
    __shared__ float s0[256], s1[256];
    s0[t] = sum; s1[t] = sq; __syncthreads();
    for (int o = 128; o > 0; o >>= 1) {
        if (t < o) { s0[t] += s0[t + o]; s1[t] += s1[t + o]; }
        __syncthreads();
    }
    float mu = s0[0] * (1.f / N_);
    float var = s1[0] * (1.f / N_) - mu * mu;
    float inv = rsqrtf(var + 1e-5f);
    float ww = w[c], bv = bb[c];
#pragma unroll
    for (int i = 0; i < 2; ++i) {
        int n = t + i * 256;
        x0[((size_t)b * N_ + n) * KP0_ + 128 + c] = f2bf((vals[i] - mu) * inv * ww + bv);
    }
}

// ---------------------------------------------------------------------------
// Weight transpose+convert: w [H][K][128] f32 -> wt [H][128][Kp] bf16 (pad 0)
// ---------------------------------------------------------------------------
template <int K, int Kp>
__global__ __launch_bounds__(128) void k_wt(const float* __restrict__ w,
                                            ushort* __restrict__ wt) {
    int hh = blockIdx.x / (Kp / 8);
    int kc = blockIdx.x % (Kp / 8);
    int o = threadIdx.x;
    bf16x8 v;
#pragma unroll
    for (int j = 0; j < 8; ++j) {
        int k = kc * 8 + j;
        float f = (k < K) ? w[((size_t)hh * K + k) * 128 + o] : 0.f;
        v[j] = (short)f2bf(f);
    }
    *(bf16x8*)(wt + ((size_t)(hh * 128 + o)) * Kp + kc * 8) = v;
}

// ---------------------------------------------------------------------------
// adj > 0 bitmask: word (b*512+n)*8 + c holds bits for m = c*64 .. c*64+63
// ---------------------------------------------------------------------------
__global__ __launch_bounds__(256) void k_mask(const float* __restrict__ adj,
                                              unsigned long long* __restrict__ mask) {
    int gid = blockIdx.x * 256 + threadIdx.x;
    float v = adj[gid];
    unsigned long long m = __ballot(v > 0.f);
    if ((threadIdx.x & 63) == 0) mask[gid >> 6] = m;
}

// ---------------------------------------------------------------------------
// MFMA GEMM + fused s/d: hpT[bh][o][n] = sum_k A[b*512+n][k] * Wt[h][o][k]
// s[bh][n] = sum_o tanh(hp)*a_src[h][o]; d likewise (fp32 acc, pre-bf16).
// bid: hh = bid&7 (head pinned to XCD), mt = bid>>3.
// ---------------------------------------------------------------------------
template <int K>
__global__ __launch_bounds__(256) void k_gemm(const ushort* __restrict__ A,
                                              const ushort* __restrict__ Wt,
                                              const float* __restrict__ asrc,
                                              const float* __restrict__ adst,
                                              ushort* __restrict__ hpT,
                                              float* __restrict__ sout,
                                              float* __restrict__ dout) {
    __shared__ ushort As[128 * 64];
    __shared__ ushort Bs[128 * 64];
    int bid = blockIdx.x;
    int hh = bid & 7;            // head (XCD-pinned)
    int mt = bid >> 3;           // 128-row tile of M=8192
    int tid = threadIdx.x;
    int wid = tid >> 6, l = tid & 63;
    int wm = wid >> 1, wn = wid & 1;

    const ushort* Ab = A + (size_t)mt * 128 * K;
    const ushort* Wb = Wt + (size_t)hh * 128 * K;

    f32x4 acc[4][4];
#pragma unroll
    for (int m = 0; m < 4; ++m)
#pragma unroll
        for (int n = 0; n < 4; ++n) acc[m][n] = (f32x4){0.f, 0.f, 0.f, 0.f};

    int srow = tid >> 3;         // 0..31
    int segp = tid & 7;          // physical 16B slot

    for (int kt = 0; kt < K / 64; ++kt) {
        int k0 = kt * 64;
#pragma unroll
        for (int it = 0; it < 4; ++it) {
            int row = it * 32 + srow;
            int segl = segp ^ (row & 7);
            __builtin_amdgcn_global_load_lds(
                (const __attribute__((address_space(1))) void*)(Ab + (size_t)row * K + k0 + segl * 8),
                (__attribute__((address_space(3))) void*)(As + (it * 32 + wid * 8) * 64),
                16, 0, 0);
            __builtin_amdgcn_global_load_lds(
                (const __attribute__((address_space(1))) void*)(Wb + (size_t)row * K + k0 + segl * 8),
                (__attribute__((address_space(3))) void*)(Bs + (it * 32 + wid * 8) * 64),
                16, 0, 0);
        }
        __syncthreads();

        int lr = l & 15;
        int kg = l >> 4;
#pragma unroll
        for (int kk = 0; kk < 2; ++kk) {
            int segl = kk * 4 + kg;
            bf16x8 a[4], b[4];
#pragma unroll
            for (int m = 0; m < 4; ++m) {
                int row = wm * 64 + m * 16 + lr;
                int sp = segl ^ (row & 7);
                a[m] = *(const bf16x8*)(As + row * 64 + sp * 8);
            }
#pragma unroll
            for (int n = 0; n < 4; ++n) {
                int row = wn * 64 + n * 16 + lr;
                int sp = segl ^ (row & 7);
                b[n] = *(const bf16x8*)(Bs + row * 64 + sp * 8);
            }
#pragma unroll
            for (int m = 0; m < 4; ++m)
#pragma unroll
                for (int n = 0; n < 4; ++n)
                    acc[m][n] = __builtin_amdgcn_mfma_f32_16x16x32_bf16(a[m], b[n], acc[m][n], 0, 0, 0);
        }
        __syncthreads();
    }

    // epilogue 1: hpT write. D col=lane&15 (o), row=(lane>>4)*4+j (n).
    int bb = mt >> 2;
    int n_in_b = (mt & 3) * 128;
    int bh = bb * H_ + hh;
    ushort* Hp = hpT + ((size_t)bh * 128) * 512;
#pragma unroll
    for (int m = 0; m < 4; ++m)
#pragma unroll
        for (int n = 0; n < 4; ++n) {
            int rr = wm * 64 + m * 16 + (l >> 4) * 4;
            int cc = wn * 64 + n * 16 + (l & 15);
            ushort4 v;
            v.x = f2bf(acc[m][n][0]);
            v.y = f2bf(acc[m][n][1]);
            v.z = f2bf(acc[m][n][2]);
            v.w = f2bf(acc[m][n][3]);
            *(ushort4*)(Hp + (size_t)cc * 512 + n_in_b + rr) = v;
        }

    // epilogue 2: fused s/d row-reduce (tanh in fp32)
    float* sP = (float*)As;          // [2][128]
    float* dP = sP + 256;            // [2][128]
    float av[4], dv[4];
#pragma unroll
    for (int n = 0; n < 4; ++n) {
        int cc = wn * 64 + n * 16 + (l & 15);
        av[n] = asrc[hh * 128 + cc];
        dv[n] = adst[hh * 128 + cc];
    }
#pragma unroll
    for (int m = 0; m < 4; ++m)
#pragma unroll
        for (int j = 0; j < 4; ++j) {
            float sv = 0.f, dvv = 0.f;
#pragma unroll
            for (int n = 0; n < 4; ++n) {
                float th = tanh_fast(acc[m][n][j]);
                sv += th * av[n];
                dvv += th * dv[n];
            }
#pragma unroll
            for (int off = 1; off < 16; off <<= 1) {
                sv += __shfl_xor(sv, off);
                dvv += __shfl_xor(dvv, off);
            }
            if ((l & 15) == 0) {
                int rr = wm * 64 + m * 16 + (l >> 4) * 4 + j;
                sP[wn * 128 + rr] = sv;
                dP[wn * 128 + rr] = dvv;
            }
        }
    __syncthreads();
    if (tid < 128) {
        sout[(size_t)bh * 512 + n_in_b + tid] = sP[tid] + sP[128 + tid];
    } else {
        int r = tid - 128;
        dout[(size_t)bh * 512 + n_in_b + r] = dP[r] + dP[128 + r];
    }
}

// ---------------------------------------------------------------------------
// Fused masked softmax + PV as a tiled GEMM with generated-A.
// grid 512: xcd=bid&7, idx=bid>>3, bh = xcd + 8*(idx&15), tile = idx>>4.
// Block: 256 threads (2x2 waves of 64x64), output tile n-128 x o-128.
// ---------------------------------------------------------------------------
template <bool L0>
__global__ __launch_bounds__(256, 2) void k_attn(const ushort* __restrict__ hpT,
                                                 const float* __restrict__ sbuf,
                                                 const float* __restrict__ dbuf,
                                                 const unsigned* __restrict__ mask32,
                                                 ushort* __restrict__ out) {
    __shared__ ushort Vbuf[128 * 64];
    __shared__ ushort Abuf[128 * 64];
    __shared__ float dsh[512];
    __shared__ float rsh[128];

    int bid = blockIdx.x;
    int xcd = bid & 7, idx = bid >> 3;
    int bh = xcd + 8 * (idx & 15);
    int tile = idx >> 4;             // 0..3
    int b = bh >> 3, hh = bh & 7;
    int n0 = tile * 128;
    int t = threadIdx.x;
    int wid = t >> 6, l = t & 63;
    int wm = wid >> 1, wn = wid & 1;
    int lr = l & 15, kg = l >> 4;

    const ushort* Vb = hpT + (size_t)bh * 128 * 512;   // [o][node]

    // per-thread softmax assignment: row 0..127, m-half 0..1
    int row = t >> 1, mh = t & 1;
    float sv = sbuf[(size_t)bh * 512 + n0 + row];
    unsigned mw[8];
#pragma unroll
    for (int c = 0; c < 8; ++c)
        mw[c] = mask32[((size_t)(b * 512 + n0 + row) << 4) + c * 2 + mh];

    // stage d
    dsh[t] = dbuf[(size_t)bh * 512 + t];
    dsh[256 + t] = dbuf[(size_t)bh * 512 + 256 + t];
    __syncthreads();

    f32x4 acc[4][4];
#pragma unroll
    for (int m = 0; m < 4; ++m)
#pragma unroll
        for (int n = 0; n < 4; ++n) acc[m][n] = (f32x4){0.f, 0.f, 0.f, 0.f};

    float rsum = 0.f;
    int srow = t >> 3, segp = t & 7;

    for (int c = 0; c < 8; ++c) {
        int m0 = c * 64;
        // stage V chunk (overlaps with softmax below; barrier drains both)
#pragma unroll
        for (int it = 0; it < 4; ++it) {
            int rrow = it * 32 + srow;
            int segl = segp ^ (rrow & 7);
            __builtin_amdgcn_global_load_lds(
                (const __attribute__((address_space(1))) void*)(Vb + (size_t)rrow * 512 + m0 + segl * 8),
                (__attribute__((address_space(3))) void*)(Vbuf + (it * 32 + wid * 8) * 64),
                16, 0, 0);
        }

        // softmax: 32 logits -> unnormalized e -> P chunk
        const float* dp = dsh + m0 + mh * 32;
        unsigned mwc = mw[c];
#pragma unroll
        for (int j = 0; j < 4; ++j) {
            f32x4 da = *(const f32x4*)(dp + j * 8);
            f32x4 db2 = *(const f32x4*)(dp + j * 8 + 4);
            float ev[8];
#pragma unroll
            for (int q = 0; q < 8; ++q) {
                float dm = (q < 4) ? da[q] : db2[q - 4];
                float lg = sv + dm;
                lg = fmaxf(lg, 0.2f * lg);           // leaky_relu(0.2)
                float e = ((mwc >> (j * 8 + q)) & 1) ? __expf(lg) : 0.f;
                rsum += e;
                ev[q] = e;
            }
            unsigned p01, p23, p45, p67;
            asm("v_cvt_pk_bf16_f32 %0, %1, %2" : "=v"(p01) : "v"(ev[0]), "v"(ev[1]));
            asm("v_cvt_pk_bf16_f32 %0, %1, %2" : "=v"(p23) : "v"(ev[2]), "v"(ev[3]));
            asm("v_cvt_pk_bf16_f32 %0, %1, %2" : "=v"(p45) : "v"(ev[4]), "v"(ev[5]));
            asm("v_cvt_pk_bf16_f32 %0, %1, %2" : "=v"(p67) : "v"(ev[6]), "v"(ev[7]));
            int s = mh * 4 + j;
            int phys = s ^ (row & 7);
            uint4 pk4 = {p01, p23, p45, p67};
            *(uint4*)((char*)Abuf + row * 128 + phys * 16) = pk4;
        }
        __syncthreads();

        // MFMA: D[o][n] += V[o][m-chunk] . P[n][m-chunk]
#pragma unroll
        for (int kk = 0; kk < 2; ++kk) {
            int s = kk * 4 + kg;
            bf16x8 a[4], bfr[4];
#pragma unroll
            for (int m = 0; m < 4; ++m) {
                int rw = wm * 64 + m * 16 + lr;
                int sp = s ^ (rw & 7);
                a[m] = *(const bf16x8*)(Vbuf + rw * 64 + sp * 8);
            }
#pragma unroll
            for (int n = 0; n < 4; ++n) {
                int rw = wn * 64 + n * 16 + lr;
                int sp = s ^ (rw & 7);
                bfr[n] = *(const bf16x8*)(Abuf + rw * 64 + sp * 8);
            }
#pragma unroll
            for (int m = 0; m < 4; ++m)
#pragma unroll
                for (int n = 0; n < 4; ++n)
                    acc[m][n] = __builtin_amdgcn_mfma_f32_16x16x32_bf16(a[m], bfr[n], acc[m][n], 0, 0, 0);
        }
        __syncthreads();
    }

    // rowsum: threads t, t^1 cover the two m-halves of row t>>1
    rsum += __shfl_xor(rsum, 1);
    if ((t & 1) == 0) rsh[row] = rsum;
    __syncthreads();

    // epilogue: normalize + (ELU) + direct ushort4 stores (D rows=o, cols=n)
#pragma unroll
    for (int n = 0; n < 4; ++n) {
        int nn = wn * 64 + n * 16 + lr;
        float ri = __frcp_rn(rsh[nn]);
        size_t orow;
        if (L0)
            orow = ((size_t)(b * 512 + n0 + nn)) * FIN1_ + hh * 128;
        else
            orow = ((size_t)bh * 512 + n0 + nn) * 128;
#pragma unroll
        for (int m = 0; m < 4; ++m) {
            int o0 = wm * 64 + m * 16 + kg * 4;
            f32x4 v = acc[m][n];
            ushort4 w;
            float f0 = v[0] * ri, f1 = v[1] * ri, f2 = v[2] * ri, f3 = v[3] * ri;
            if (L0) {
                f0 = (f0 > 0.f) ? f0 : expm1f(f0);
                f1 = (f1 > 0.f) ? f1 : expm1f(f1);
                f2 = (f2 > 0.f) ? f2 : expm1f(f2);
                f3 = (f3 > 0.f) ? f3 : expm1f(f3);
            }
            w.x = f2bf(f0); w.y = f2bf(f1); w.z = f2bf(f2); w.w = f2bf(f3);
            *(ushort4*)(out + orow + o0) = w;
        }
    }
}

// ---------------------------------------------------------------------------
// mean over heads (bf16 in) + log_softmax over channels(128)
// ---------------------------------------------------------------------------
__global__ __launch_bounds__(128) void k_out(const ushort* __restrict__ o1,
                                             float* __restrict__ out) {
    int row = blockIdx.x;       // b*512+n
    int b = row >> 9, n = row & 511;
    int t = threadIdx.x;
    float v = 0.f;
#pragma unroll
    for (int hh = 0; hh < H_; ++hh)
        v += bf2f(o1[((size_t)(b * H_ + hh) * N_ + n) * O_ + t]);
    v *= 0.125f;
    float m = v;
#pragma unroll
    for (int off = 32; off > 0; off >>= 1) m = fmaxf(m, __shfl_down(m, off));
    __shared__ float red[4];
    if ((t & 63) == 0) red[t >> 6] = m;
    __syncthreads();
    float rm = fmaxf(red[0], red[1]);
    float e = __expf(v - rm);
    float ss = e;
#pragma unroll
    for (int off = 32; off > 0; off >>= 1) ss += __shfl_down(ss, off);
    if ((t & 63) == 0) red[2 + (t >> 6)] = ss;
    __syncthreads();
    float rs2 = red[2] + red[3];
    out[(size_t)row * O_ + t] = v - rm - logf(rs2);
}

// ---------------------------------------------------------------------------
extern "C" void kernel_launch(void* const* d_in, const int* in_sizes, int n_in,
                              void* d_out, int out_size, void* d_ws, size_t ws_size,
                              hipStream_t stream) {
    const int*   verts = (const int*)d_in[0];
    const float* adj   = (const float*)d_in[1];
    const float* h     = (const float*)d_in[2];
    const float* ue    = (const float*)d_in[3];
    const float* table = (const float*)d_in[4];
    const float* n1w   = (const float*)d_in[5];
    const float* n1b   = (const float*)d_in[6];
    const float* n2w   = (const float*)d_in[7];
    const float* n2b   = (const float*)d_in[8];
    const float* w0    = (const float*)d_in[9];
    const float* as0   = (const float*)d_in[10];
    const float* ad0   = (const float*)d_in[11];
    const float* w1    = (const float*)d_in[12];
    const float* as1   = (const float*)d_in[13];
    const float* ad1   = (const float*)d_in[14];
    float* out = (float*)d_out;

    // workspace layout (ushort units)
    ushort* x0p  = (ushort*)d_ws;                 // 1,572,864
    ushort* wt0  = x0p + 1572864;                 // 196,608
    ushort* wt1  = wt0 + 196608;                  // 1,048,576
    ushort* hpT  = wt1 + 1048576;                 // 8,388,608
    ushort* x1bf = hpT + 8388608;                 // 8,388,608
    ushort* o1   = x1bf + 8388608;                // 8,388,608
    unsigned long long* mask = (unsigned long long*)(o1 + 8388608);  // 65,536 words
    float* sb = (float*)(mask + 65536);           // 65,536 f
    float* db = sb + 65536;                       // 65,536 f

    hipLaunchKernelGGL(k_copy_h,   dim3(2048), dim3(256), 0, stream, h, x0p);
    hipLaunchKernelGGL(k_emb_norm, dim3(1024), dim3(256), 0, stream, verts, table, n1w, n1b, x0p);
    hipLaunchKernelGGL(k_ue_norm,  dim3(48),   dim3(256), 0, stream, ue, n2w, n2b, x0p);
    hipLaunchKernelGGL((k_wt<FIN0_, KP0_>), dim3(8 * (KP0_ / 8)), dim3(128), 0, stream, w0, wt0);
    hipLaunchKernelGGL((k_wt<FIN1_, FIN1_>), dim3(8 * (FIN1_ / 8)), dim3(128), 0, stream, w1, wt1);
    hipLaunchKernelGGL(k_mask, dim3(16384), dim3(256), 0, stream, adj, mask);

    // layer 0 (s/d fused into GEMM epilogue)
    hipLaunchKernelGGL((k_gemm<KP0_>), dim3(512), dim3(256), 0, stream,
                       x0p, wt0, as0, ad0, hpT, sb, db);
    hipLaunchKernelGGL((k_attn<true>), dim3(512), dim3(256), 0, stream,
                       hpT, sb, db, (const unsigned*)mask, x1bf);

    // layer 1
    hipLaunchKernelGGL((k_gemm<FIN1_>), dim3(512), dim3(256), 0, stream,
                       x1bf, wt1, as1, ad1, hpT, sb, db);
    hipLaunchKernelGGL((k_attn<false>), dim3(512), dim3(256), 0, stream,
                       hpT, sb, db, (const unsigned*)mask, o1);

    // mean over heads + log_softmax
    hipLaunchKernelGGL(k_out, dim3(8192), dim3(128), 0, stream, o1, out);
}